// Round 4
// baseline (554.388 us; speedup 1.0000x reference)
//
#include <hip/hip_runtime.h>

#define NV 400000
#define KOFF 27
#define CD 64
#define DD 128
#define HH 128
#define WW 128
#define TABN (2*DD*HH*WW)
#define EPSV 1e-5f

typedef _Float16 f16;
typedef _Float16 f16x8 __attribute__((ext_vector_type(8)));
typedef float f32x16 __attribute__((ext_vector_type(16)));

// ---- workspace layout (bytes) ----
#define OFF_NBR   0ull
#define OFF_X1    43200000ull
#define OFF_X2    94400000ull
#define OFF_TAB   94400000ull     // table dead before x2 written
#define OFF_W2T   145600000ull
#define OFF_W3T   145821184ull
#define OFF_ZERO  146042368ull

#define GLDS16(gp, lp) __builtin_amdgcn_global_load_lds( \
    (__attribute__((address_space(1))) void*)(gp), \
    (__attribute__((address_space(3))) void*)(lp), 16, 0, 0)

// ---- init: table=-1; weights -> f16 chunk-major wTg[k][cin/8][cout][cin&7] ----
__global__ void k_init(const float* __restrict__ w2, const float* __restrict__ w3,
                       int* __restrict__ tab, f16* __restrict__ w2t,
                       f16* __restrict__ w3t, f16* __restrict__ zrow) {
    int t = blockIdx.x * 256 + threadIdx.x;           // grid: 4096*256
    int4* tv = (int4*)tab;
    if (t < TABN / 4) tv[t] = make_int4(-1, -1, -1, -1);
    if (t < KOFF * CD * CD) {
        int k = t >> 12, r = t & 4095, c = r >> 6, ci = r & 63;
        int d = (k << 12) + ((ci >> 3) << 9) + (c << 3) + (ci & 7);
        w2t[d] = (f16)w2[(k << 12) + (ci << 6) + c];
        w3t[d] = (f16)w3[(k << 12) + (ci << 6) + c];
    }
    if (t < CD) zrow[t] = (f16)0.f;
}

__global__ void k_scatter(const int4* __restrict__ coords, int* __restrict__ tab) {
    int i = blockIdx.x * 256 + threadIdx.x;
    if (i >= NV) return;
    int4 c = coords[i];  // (b,z,y,x)
    int flat = ((c.x * DD + c.y) * HH + c.z) * WW + c.w;
    tab[flat] = i;
}

__global__ void k_nbr(const int4* __restrict__ coords, const int* __restrict__ tab,
                      int* __restrict__ nbr) {
    int i = blockIdx.x * 256 + threadIdx.x;
    if (i >= NV) return;
    int4 c = coords[i];
    int k = 0;
    #pragma unroll
    for (int dz = -1; dz <= 1; dz++)
    #pragma unroll
    for (int dy = -1; dy <= 1; dy++)
    #pragma unroll
    for (int dx = -1; dx <= 1; dx++) {
        int z = c.y + dz, y = c.z + dy, x = c.w + dx;
        int idx = -1;
        if (z >= 0 && z < DD && y >= 0 && y < HH && x >= 0 && x < WW)
            idx = tab[((c.x * DD + z) * HH + y) * WW + x];
        nbr[k * NV + i] = idx;
        k++;
    }
}

// ---- layer 1: one thread per voxel, acc[64] in VGPRs, scalar weights ----
__global__ __launch_bounds__(256) void k_layer1(
        const float* __restrict__ feats, const int* __restrict__ nbr,
        const float* __restrict__ w1, const float* __restrict__ b1,
        const float* __restrict__ g1, const float* __restrict__ be1,
        const float* __restrict__ m1, const float* __restrict__ v1,
        f16* __restrict__ x1) {
    int i = blockIdx.x * 256 + threadIdx.x;
    bool act = (i < NV);
    int ii = act ? i : 0;

    float acc[CD];
    #pragma unroll
    for (int c = 0; c < CD; c++) acc[c] = 0.f;

    #pragma unroll
    for (int k = 0; k < KOFF; k++) {
        int idx = act ? nbr[k * NV + ii] : -1;
        float fk = (idx >= 0) ? feats[idx] : 0.f;
        #pragma unroll
        for (int c = 0; c < CD; c++)
            acc[c] = fmaf(fk, w1[k * CD + c], acc[c]);
    }
    if (!act) return;

    #pragma unroll
    for (int c0 = 0; c0 < CD; c0 += 8) {
        f16x8 o;
        #pragma unroll
        for (int j = 0; j < 8; j++) {
            int c = c0 + j;
            float sc = g1[c] * rsqrtf(v1[c] + EPSV);
            float y = (acc[c] - m1[c] + b1[c]) * sc + be1[c];
            o[j] = (f16)fmaxf(y, 0.f);
        }
        *(f16x8*)(x1 + (size_t)i * CD + c0) = o;
    }
}

// ---- conv v10: pair-k phases — 14 barriers instead of 27.
// Three structural variants (v6/v7/v9) all pinned at ~118us, MfmaUtil 31%,
// with LDS traffic, gather-request count, occupancy, and drain policy each
// varied independently. Survivors: per-body barrier convoy, gather latency.
// v10 halves the phase count: each phase processes k=2p,2p+1 with B quad-
// buffered (2 halves x 2 tiles x 8KB = 32KB LDS, unioned with epilogue).
// A-fragments rotate through 3 slots (aF[(k)%3]) so only 48 VGPRs of A live;
// A(2p+2) prefetched at phase start, A(2p+3) mid-phase (between MFMA blocks).
// Counted waits per 14-op phase segment (4 GLDS + 4 A + 2 nbr + 4 midA):
// VMW(12) phase 0, VMW(10) phases 1..11, VMW(9) phase 12, VMW(4) last.
// Stage-after-barrier ordering (v9's proven-safe rule) throughout.
// ABL template param: de-randomized ablation probe (all A-loads hit the
// L1-hot zero row; identical instruction counts) for bottleneck decode.
#define MFMA3216(a, b, c) __builtin_amdgcn_mfma_f32_32x32x16_f16(a, b, c, 0, 0, 0)

#define VMW_(n) asm volatile("s_waitcnt vmcnt(" #n ")" ::: "memory")
#define VMW(n) VMW_(n)

#define ALOAD(IDX, SLOT)                                                        \
  {                                                                             \
    const char* ap = ((!ABL && (IDX) >= 0)                                      \
        ? (const char*)xin + (size_t)(IDX) * 128                                \
        : (const char*)zr) + g * 16;                                            \
    _Pragma("unroll")                                                           \
    for (int ks = 0; ks < 4; ks++)                                              \
      aF[(SLOT)][ks] = *(const f16x8*)(ap + ks * 32);                           \
  }

#define MFMABLK(HALF, TILE, SLOT)                                               \
  {                                                                             \
    __builtin_amdgcn_s_setprio(1);                                              \
    _Pragma("unroll")                                                           \
    for (int ks = 0; ks < 4; ks++) {                                            \
      const char* bp = (const char*)bbuf + (HALF) * 16384 + (TILE) * 8192       \
                       + (2 * ks + g) * 1024;                                   \
      f16x8 b0 = *(const f16x8*)(bp + ml * 16);                                 \
      f16x8 b1 = *(const f16x8*)(bp + 512 + ml * 16);                           \
      acc[0] = MFMA3216(aF[(SLOT)][ks], b0, acc[0]);                            \
      acc[1] = MFMA3216(aF[(SLOT)][ks], b1, acc[1]);                            \
    }                                                                           \
    __builtin_amdgcn_s_setprio(0);                                              \
  }

#define CONV_PHASE(P, WN)                                                       \
  {                                                                             \
    VMW(WN);                                                                    \
    __builtin_amdgcn_s_barrier();                                               \
    asm volatile("" ::: "memory");                                              \
    if ((P) <= 11) {                                                            \
      _Pragma("unroll")                                                         \
      for (int tt = 0; tt < 2; tt++)                                            \
        _Pragma("unroll")                                                       \
        for (int it = 0; it < 2; it++) {                                        \
          const char* gp = (const char*)wT + ((size_t)(2 * (P) + 2 + tt) * 8192 \
                            + it * 4096 + tid * 16);                            \
          char* lp = (char*)bbuf + (1 - ((P) & 1)) * 16384 + tt * 8192          \
                            + it * 4096 + wv * 1024;                            \
          GLDS16(gp, lp);                                                       \
        }                                                                       \
    } else if ((P) == 12) {                                                     \
      _Pragma("unroll")                                                         \
      for (int it = 0; it < 2; it++) {                                          \
        const char* gp = (const char*)wT + (26ull * 8192 + it * 4096 + tid * 16);\
        char* lp = (char*)bbuf + (1 - ((P) & 1)) * 16384 + it * 4096 + wv * 1024;\
        GLDS16(gp, lp);                                                         \
      }                                                                         \
    }                                                                           \
    if ((P) <= 12) ALOAD(idxN0, (2 * (P) + 2) % 3);                             \
    int iwN0 = idxN0, iwN1 = idxN1;                                             \
    if ((P) <= 10) {                                                            \
      iwN0 = nbr[(size_t)(2 * (P) + 4) * NV + row];                             \
      iwN1 = nbr[(size_t)(2 * (P) + 5) * NV + row];                             \
    } else if ((P) == 11) {                                                     \
      iwN0 = nbr[26ull * NV + row];                                             \
    }                                                                           \
    asm volatile("" ::: "memory");                                              \
    MFMABLK((P) & 1, 0, (2 * (P)) % 3);                                         \
    asm volatile("" ::: "memory");                                              \
    if ((P) <= 11) ALOAD(idxN1, (2 * (P) + 3) % 3);                             \
    asm volatile("" ::: "memory");                                              \
    MFMABLK((P) & 1, 1, (2 * (P) + 1) % 3);                                     \
    idxN0 = iwN0;                                                               \
    idxN1 = iwN1;                                                               \
  }

static_assert(NV % 128 == 0, "grid must tile exactly");

template <bool OUTF32, bool ABL>
__global__ __launch_bounds__(256, 4) void k_conv(
        const f16* __restrict__ xin, const f16* __restrict__ wT,
        const int* __restrict__ nbr, const f16* __restrict__ zr,
        const float* __restrict__ bb, const float* __restrict__ gg,
        const float* __restrict__ bee, const float* __restrict__ mm,
        const float* __restrict__ vv, void* __restrict__ outp) {
    // 32 KB: B quad-buffer [2 halves][2 tiles][8192] during the loop; the
    // same bytes are the 16 KB epilogue transpose scratch after the last MFMA.
    __shared__ __align__(16) unsigned char smem[32768];
    unsigned char* bbuf = smem;
    unsigned char* sS = smem;

    const int tid = threadIdx.x;
    const int lane = tid & 63;
    const int wv = tid >> 6;
    const int g = lane >> 5;
    const int ml = lane & 31;
    const int vbase = blockIdx.x * 128;       // grid 3125, exact fit
    const int row = vbase + wv * 32 + ml;     // this lane's A-row voxel

    f32x16 acc[2];
    #pragma unroll
    for (int b = 0; b < 2; b++) acc[b] = (f32x16)(0.f);

    f16x8 aF[3][4];
    int idxN0, idxN1;

    // prologue: stage B(0),B(1) into half 0; A(0)->slot0, A(1)->slot1;
    // idx(2)->idxN0, idx(3)->idxN1.
    #pragma unroll
    for (int tt = 0; tt < 2; tt++)
        #pragma unroll
        for (int it = 0; it < 2; it++) {
            const char* gp = (const char*)wT + ((size_t)tt * 8192 + it * 4096 + tid * 16);
            char* lp = (char*)bbuf + tt * 8192 + it * 4096 + wv * 1024;
            GLDS16(gp, lp);
        }
    asm volatile("" ::: "memory");
    {
        int iw0 = nbr[row];
        int iw1 = nbr[(size_t)NV + row];
        ALOAD(iw0, 0);
        ALOAD(iw1, 1);
        idxN0 = nbr[2ull * NV + row];
        idxN1 = nbr[3ull * NV + row];
    }
    asm volatile("" ::: "memory");

    CONV_PHASE(0, 12)
    CONV_PHASE(1, 10)
    CONV_PHASE(2, 10)
    CONV_PHASE(3, 10)
    CONV_PHASE(4, 10)
    CONV_PHASE(5, 10)
    CONV_PHASE(6, 10)
    CONV_PHASE(7, 10)
    CONV_PHASE(8, 10)
    CONV_PHASE(9, 10)
    CONV_PHASE(10, 10)
    CONV_PHASE(11, 10)
    CONV_PHASE(12, 9)
    // last phase: k=26 alone, staged by phase 12 into half 1 tile 0, slot 2
    {
        VMW(4);
        __builtin_amdgcn_s_barrier();
        asm volatile("" ::: "memory");
        MFMABLK(1, 0, 2);
    }

    // epilogue: BN+ReLU -> LDS transpose -> vectorized stores
    if (!OUTF32) {
        __syncthreads();
        #pragma unroll
        for (int nt = 0; nt < 2; nt++) {
            int cn = nt * 32 + ml;
            float sc = gg[cn] * rsqrtf(vv[cn] + EPSV);
            float sh = (bb[cn] - mm[cn]) * sc + bee[cn];
            #pragma unroll
            for (int r = 0; r < 16; r++) {
                int rowl = wv * 32 + (r & 3) + 8 * (r >> 2) + 4 * g;
                float y = fmaxf(acc[nt][r] * sc + sh, 0.f);
                *(f16*)(sS + rowl * 128 + cn * 2) = (f16)y;
            }
        }
        __syncthreads();
        char* gb = (char*)outp + (size_t)vbase * 128;
        #pragma unroll
        for (int it = 0; it < 4; it++) {
            int s = it * 256 + tid;
            *(float4*)(gb + s * 16) = *(const float4*)(sS + s * 16);
        }
    } else {
        #pragma unroll 1
        for (int p = 0; p < 2; p++) {
            __syncthreads();
            if ((wv >> 1) == p) {
                int lw = wv & 1;
                #pragma unroll
                for (int nt = 0; nt < 2; nt++) {
                    int cn = nt * 32 + ml;
                    float sc = gg[cn] * rsqrtf(vv[cn] + EPSV);
                    float sh = (bb[cn] - mm[cn]) * sc + bee[cn];
                    #pragma unroll
                    for (int r = 0; r < 16; r++) {
                        int rowl = lw * 32 + (r & 3) + 8 * (r >> 2) + 4 * g;
                        float y = fmaxf(acc[nt][r] * sc + sh, 0.f);
                        *(float*)(sS + rowl * 256 + cn * 4) = y;
                    }
                }
            }
            __syncthreads();
            char* gb = (char*)outp + ((size_t)vbase + p * 64) * 256;
            #pragma unroll
            for (int it = 0; it < 4; it++) {
                int s = it * 256 + tid;
                *(float4*)(gb + s * 16) = *(const float4*)(sS + s * 16);
            }
        }
    }
}

extern "C" void kernel_launch(void* const* d_in, const int* in_sizes, int n_in,
                              void* d_out, int out_size, void* d_ws, size_t ws_size,
                              hipStream_t stream) {
    (void)in_sizes; (void)n_in; (void)out_size; (void)ws_size;
    const float* feats = (const float*)d_in[0];
    const int4* coords = (const int4*)d_in[1];
    const float* w1 = (const float*)d_in[2];
    const float* b1 = (const float*)d_in[3];
    const float* g1 = (const float*)d_in[4];
    const float* be1 = (const float*)d_in[5];
    const float* m1 = (const float*)d_in[6];
    const float* v1 = (const float*)d_in[7];
    const float* w2 = (const float*)d_in[8];
    const float* b2 = (const float*)d_in[9];
    const float* g2 = (const float*)d_in[10];
    const float* be2 = (const float*)d_in[11];
    const float* m2 = (const float*)d_in[12];
    const float* v2 = (const float*)d_in[13];
    const float* w3 = (const float*)d_in[14];
    const float* b3 = (const float*)d_in[15];
    const float* g3 = (const float*)d_in[16];
    const float* be3 = (const float*)d_in[17];
    const float* m3 = (const float*)d_in[18];
    const float* v3 = (const float*)d_in[19];

    char* ws = (char*)d_ws;
    int* nbr  = (int*)(ws + OFF_NBR);
    f16* x1   = (f16*)(ws + OFF_X1);
    f16* x2   = (f16*)(ws + OFF_X2);
    int* tab  = (int*)(ws + OFF_TAB);
    f16* w2t  = (f16*)(ws + OFF_W2T);
    f16* w3t  = (f16*)(ws + OFF_W3T);
    f16* zrow = (f16*)(ws + OFF_ZERO);

    k_init<<<4096, 256, 0, stream>>>(w2, w3, tab, w2t, w3t, zrow);
    k_scatter<<<(NV + 255) / 256, 256, 0, stream>>>(coords, tab);
    k_nbr<<<(NV + 255) / 256, 256, 0, stream>>>(coords, tab, nbr);
    k_layer1<<<(NV + 255) / 256, 256, 0, stream>>>(feats, nbr, w1, b1, g1, be1, m1, v1, x1);
    const int convgrid = NV / 128;  // 3125, exact
    // Ablation probe: identical structure, de-randomized A-loads (all hit the
    // L1-hot zero row). Writes the x2 region, which the REAL layer-2 dispatch
    // below fully overwrites (400000*128B = exactly the region) -> harmless.
    // Decode: probe_dur ~= real_dur  => gather randomness irrelevant;
    //         probe_dur << real_dur  => gather latency/BW is the wall.
    k_conv<false, true><<<convgrid, 256, 0, stream>>>(x1, w2t, nbr, zrow, b2, g2, be2, m2, v2, (void*)x2);
    k_conv<false, false><<<convgrid, 256, 0, stream>>>(x1, w2t, nbr, zrow, b2, g2, be2, m2, v2, (void*)x2);
    k_conv<true, false><<<convgrid, 256, 0, stream>>>(x2, w3t, nbr, zrow, b3, g3, be3, m3, v3, d_out);
}

// Round 5
// 498.389 us; speedup vs baseline: 1.1124x; 1.1124x over previous
//
#include <hip/hip_runtime.h>

#define NV 400000
#define KOFF 27
#define CD 64
#define DD 128
#define HH 128
#define WW 128
#define TABN (2*DD*HH*WW)
#define EPSV 1e-5f

typedef _Float16 f16;
typedef _Float16 f16x8 __attribute__((ext_vector_type(8)));
typedef float f32x16 __attribute__((ext_vector_type(16)));

// ---- workspace layout (bytes) ----
#define OFF_NBR   0ull
#define OFF_X1    43200000ull
#define OFF_X2    94400000ull
#define OFF_TAB   94400000ull     // table dead before x2 written
#define OFF_HIST  111177216ull    // 64K cells * 4B, inside x2 region (dead pre-conv2)
#define OFF_FS    111439360ull    // sorted feats, 1.6MB, inside x2 region (dead pre-conv2)
#define OFF_W2T   145600000ull
#define OFF_W3T   145821184ull
#define OFF_ZERO  146042368ull

#define GLDS16(gp, lp) __builtin_amdgcn_global_load_lds( \
    (__attribute__((address_space(1))) void*)(gp), \
    (__attribute__((address_space(3))) void*)(lp), 16, 0, 0)

// cell = (b, z/4, y/4, x/4) -> 2*32*32*32 = 65536 spatial buckets
__device__ __forceinline__ int cell_of(int4 c) {
    return ((c.x * 32 + (c.y >> 2)) * 32 + (c.z >> 2)) * 32 + (c.w >> 2);
}

// ---- init: table=-1; hist=0; weights -> f16 chunk-major wTg[k][cin/8][cout][cin&7]
__global__ void k_init(const float* __restrict__ w2, const float* __restrict__ w3,
                       int* __restrict__ tab, f16* __restrict__ w2t,
                       f16* __restrict__ w3t, f16* __restrict__ zrow,
                       int* __restrict__ hist) {
    int t = blockIdx.x * 256 + threadIdx.x;           // grid: 4096*256
    int4* tv = (int4*)tab;
    if (t < TABN / 4) tv[t] = make_int4(-1, -1, -1, -1);
    if (t < 65536) hist[t] = 0;
    if (t < KOFF * CD * CD) {
        int k = t >> 12, r = t & 4095, c = r >> 6, ci = r & 63;
        int d = (k << 12) + ((ci >> 3) << 9) + (c << 3) + (ci & 7);
        w2t[d] = (f16)w2[(k << 12) + (ci << 6) + c];
        w3t[d] = (f16)w3[(k << 12) + (ci << 6) + c];
    }
    if (t < CD) zrow[t] = (f16)0.f;
}

// ---- spatial counting-sort: hist -> scan -> rank assignment ----
__global__ void k_hist(const int4* __restrict__ coords, int* __restrict__ hist) {
    int i = blockIdx.x * 256 + threadIdx.x;
    if (i >= NV) return;
    atomicAdd(&hist[cell_of(coords[i])], 1);
}

// exclusive prefix sum over 65536 ints, single workgroup of 1024 threads
__global__ __launch_bounds__(1024) void k_scan(int* __restrict__ hist) {
    __shared__ int part[1024];
    int t = threadIdx.x;
    int base = t * 64;
    int s = 0;
    #pragma unroll
    for (int j = 0; j < 64; j++) s += hist[base + j];
    part[t] = s;
    __syncthreads();
    for (int off = 1; off < 1024; off <<= 1) {
        int v = (t >= off) ? part[t - off] : 0;
        __syncthreads();
        part[t] += v;
        __syncthreads();
    }
    int ex = (t == 0) ? 0 : part[t - 1];
    #pragma unroll
    for (int j = 0; j < 64; j++) {
        int h = hist[base + j];
        hist[base + j] = ex;
        ex += h;
    }
}

// rank r = cell-contiguous position. Writes:
//   tab[site] = r        (neighbor table in RANK space)
//   nbr[13*NV + r] = i   (k=13 is always self -> slot stores ORIG index:
//                         the scatter-back permutation, zero extra memory)
//   feats_s[r] = feats[i] (sorted features for layer 1)
__global__ void k_rank(const int4* __restrict__ coords, const float* __restrict__ feats,
                       int* __restrict__ hist, int* __restrict__ tab,
                       int* __restrict__ nbr, float* __restrict__ feats_s) {
    int i = blockIdx.x * 256 + threadIdx.x;
    if (i >= NV) return;
    int4 c = coords[i];
    int r = atomicAdd(&hist[cell_of(c)], 1);
    int flat = ((c.x * DD + c.y) * HH + c.z) * WW + c.w;
    tab[flat] = r;
    nbr[13 * (size_t)NV + r] = i;
    feats_s[r] = feats[i];
}

// neighbor rulebook in rank space; iterates SORTED order (local tab reads).
// k=13 skipped (slot holds orig index).
__global__ void k_nbr2(const int4* __restrict__ coords, const int* __restrict__ tab,
                       int* __restrict__ nbr) {
    int r = blockIdx.x * 256 + threadIdx.x;
    if (r >= NV) return;
    int orig = nbr[13 * (size_t)NV + r];
    int4 c = coords[orig];
    int k = 0;
    #pragma unroll
    for (int dz = -1; dz <= 1; dz++)
    #pragma unroll
    for (int dy = -1; dy <= 1; dy++)
    #pragma unroll
    for (int dx = -1; dx <= 1; dx++) {
        if (k != 13) {
            int z = c.y + dz, y = c.z + dy, x = c.w + dx;
            int idx = -1;
            if (z >= 0 && z < DD && y >= 0 && y < HH && x >= 0 && x < WW)
                idx = tab[((c.x * DD + z) * HH + y) * WW + x];
            nbr[(size_t)k * NV + r] = idx;
        }
        k++;
    }
}

// ---- layer 1 (rank space): one thread per sorted voxel ----
__global__ __launch_bounds__(256) void k_layer1(
        const float* __restrict__ feats_s, const int* __restrict__ nbr,
        const float* __restrict__ w1, const float* __restrict__ b1,
        const float* __restrict__ g1, const float* __restrict__ be1,
        const float* __restrict__ m1, const float* __restrict__ v1,
        f16* __restrict__ x1) {
    int i = blockIdx.x * 256 + threadIdx.x;   // i = rank
    bool act = (i < NV);
    int ii = act ? i : 0;

    float acc[CD];
    #pragma unroll
    for (int c = 0; c < CD; c++) acc[c] = 0.f;

    #pragma unroll
    for (int k = 0; k < KOFF; k++) {
        int idx = (k == 13) ? ii : (act ? nbr[(size_t)k * NV + ii] : -1);
        float fk = (idx >= 0) ? feats_s[idx] : 0.f;
        #pragma unroll
        for (int c = 0; c < CD; c++)
            acc[c] = fmaf(fk, w1[k * CD + c], acc[c]);
    }
    if (!act) return;

    #pragma unroll
    for (int c0 = 0; c0 < CD; c0 += 8) {
        f16x8 o;
        #pragma unroll
        for (int j = 0; j < 8; j++) {
            int c = c0 + j;
            float sc = g1[c] * rsqrtf(v1[c] + EPSV);
            float y = (acc[c] - m1[c] + b1[c]) * sc + be1[c];
            o[j] = (f16)fmaxf(y, 0.f);
        }
        *(f16x8*)(x1 + (size_t)i * CD + c0) = o;
    }
}

// ---- conv v11: v9 pipeline + rank-space locality.
// R4 ablation: de-randomized A-gather = ~54us vs real 119us -> gather locality
// IS the wall (barrier count, occupancy, drain policy all refuted separately).
// Voxels are now cell-sorted, so a wave's 32 rows + all 27 offsets' neighbors
// sit in a small rank window -> L1/L2 hits instead of random L3.
// XCD-chunked bijective swizzle keeps each XCD's window in its own L2.
// k=13: idx = row (self) at compile time; the nbr[13] slot carries the orig
// index, loaded by body 11's prefetch (op counts unchanged -> VMW analysis
// identical to v9: 2 GLDS + 4 A + 1 nbr per body; 6/5...5/4).
// OUTF32 epilogue scatters rows back to original order via nbr[13].
#define MFMA3216(a, b, c) __builtin_amdgcn_mfma_f32_32x32x16_f16(a, b, c, 0, 0, 0)

#define VMW_(n) asm volatile("s_waitcnt vmcnt(" #n ")" ::: "memory")
#define VMW(n) VMW_(n)

#define CONV_BODY(K, WN)                                                        \
  {                                                                             \
    VMW(WN);                                                                    \
    __builtin_amdgcn_s_barrier();                                               \
    asm volatile("" ::: "memory");                                              \
    if ((K) + 1 < KOFF) {                                                       \
      _Pragma("unroll")                                                         \
      for (int it = 0; it < 2; it++) {                                          \
        const char* gp = (const char*)wT + ((size_t)((K) + 1) * 8192            \
                          + it * 4096 + tid * 16);                              \
        char* lp = (char*)bbuf + (((K) + 1) & 1) * 8192 + it * 4096 + wv * 1024;\
        GLDS16(gp, lp);                                                         \
      }                                                                         \
      const int aidx = ((K) + 1 == 13) ? row : idxN;                            \
      const char* ap = ((aidx >= 0)                                             \
          ? (const char*)xin + (size_t)aidx * 128                               \
          : (const char*)zr) + g * 16;                                          \
      _Pragma("unroll")                                                         \
      for (int ks = 0; ks < 4; ks++)                                            \
        aF[((K) + 1) & 1][ks] = *(const f16x8*)(ap + ks * 32);                  \
    }                                                                           \
    int iwN = idxN;                                                             \
    if ((K) + 2 < KOFF)                                                         \
      iwN = nbr[(size_t)((K) + 2) * NV + row];                                  \
    asm volatile("" ::: "memory");                                              \
    __builtin_amdgcn_s_setprio(1);                                              \
    _Pragma("unroll")                                                           \
    for (int ks = 0; ks < 4; ks++) {                                            \
      const char* bp = (const char*)bbuf + ((K) & 1) * 8192                     \
                       + (2 * ks + g) * 1024;                                   \
      f16x8 b0 = *(const f16x8*)(bp + ml * 16);                                 \
      f16x8 b1 = *(const f16x8*)(bp + 512 + ml * 16);                           \
      acc[0] = MFMA3216(aF[(K) & 1][ks], b0, acc[0]);                           \
      acc[1] = MFMA3216(aF[(K) & 1][ks], b1, acc[1]);                           \
    }                                                                           \
    __builtin_amdgcn_s_setprio(0);                                              \
    idxN = iwN;                                                                 \
  }

static_assert(NV % 128 == 0, "grid must tile exactly");

template <bool OUTF32>
__global__ __launch_bounds__(256, 5) void k_conv(
        const f16* __restrict__ xin, const f16* __restrict__ wT,
        const int* __restrict__ nbr, const f16* __restrict__ zr,
        const float* __restrict__ bb, const float* __restrict__ gg,
        const float* __restrict__ bee, const float* __restrict__ mm,
        const float* __restrict__ vv, void* __restrict__ outp) {
    // 16 KB: B double-buffer [2][8192] during the loop; same bytes are the
    // epilogue transpose scratch after the last MFMA.
    __shared__ __align__(16) unsigned char smem[16384];
    unsigned char* bbuf = smem;
    unsigned char* sS = smem;

    const int tid = threadIdx.x;
    const int lane = tid & 63;
    const int wv = tid >> 6;
    const int g = lane >> 5;
    const int ml = lane & 31;
    // bijective XCD-chunked swizzle: grid 3125 = 8*390 + 5; first 5 XCDs get
    // 391 contiguous blocks, rest 390 -> each XCD walks its own rank window.
    int bid;
    {
        int x = blockIdx.x & 7, j = blockIdx.x >> 3;
        bid = (x < 5 ? x * 391 : 5 * 391 + (x - 5) * 390) + j;
    }
    const int vbase = bid * 128;
    const int row = vbase + wv * 32 + ml;     // this lane's A-row (rank space)

    f32x16 acc[2];
    #pragma unroll
    for (int b = 0; b < 2; b++) acc[b] = (f32x16)(0.f);

    f16x8 aF[2][4];
    int idxN;

    // prologue: stage B(0); fence; A(0) -> aF[0]; idx(1) -> idxN; fence
    #pragma unroll
    for (int it = 0; it < 2; it++) {
        const char* gp = (const char*)wT + ((size_t)it * 4096 + tid * 16);
        char* lp = (char*)bbuf + it * 4096 + wv * 1024;
        GLDS16(gp, lp);
    }
    asm volatile("" ::: "memory");
    {
        int iw0 = nbr[row];
        idxN = nbr[(size_t)NV + row];
        const char* ap = ((iw0 >= 0)
            ? (const char*)xin + (size_t)iw0 * 128
            : (const char*)zr) + g * 16;
        #pragma unroll
        for (int ks = 0; ks < 4; ks++)
            aF[0][ks] = *(const f16x8*)(ap + ks * 32);
    }
    asm volatile("" ::: "memory");

    CONV_BODY(0, 6)
    CONV_BODY(1, 5)
    CONV_BODY(2, 5)
    CONV_BODY(3, 5)
    CONV_BODY(4, 5)
    CONV_BODY(5, 5)
    CONV_BODY(6, 5)
    CONV_BODY(7, 5)
    CONV_BODY(8, 5)
    CONV_BODY(9, 5)
    CONV_BODY(10, 5)
    CONV_BODY(11, 5)
    CONV_BODY(12, 5)
    CONV_BODY(13, 5)
    CONV_BODY(14, 5)
    CONV_BODY(15, 5)
    CONV_BODY(16, 5)
    CONV_BODY(17, 5)
    CONV_BODY(18, 5)
    CONV_BODY(19, 5)
    CONV_BODY(20, 5)
    CONV_BODY(21, 5)
    CONV_BODY(22, 5)
    CONV_BODY(23, 5)
    CONV_BODY(24, 5)
    CONV_BODY(25, 5)
    CONV_BODY(26, 4)

    // epilogue: BN+ReLU -> LDS transpose -> vectorized stores
    if (!OUTF32) {
        __syncthreads();
        #pragma unroll
        for (int nt = 0; nt < 2; nt++) {
            int cn = nt * 32 + ml;
            float sc = gg[cn] * rsqrtf(vv[cn] + EPSV);
            float sh = (bb[cn] - mm[cn]) * sc + bee[cn];
            #pragma unroll
            for (int r = 0; r < 16; r++) {
                int rowl = wv * 32 + (r & 3) + 8 * (r >> 2) + 4 * g;
                float y = fmaxf(acc[nt][r] * sc + sh, 0.f);
                *(f16*)(sS + rowl * 128 + cn * 2) = (f16)y;
            }
        }
        __syncthreads();
        char* gb = (char*)outp + (size_t)vbase * 128;
        #pragma unroll
        for (int it = 0; it < 4; it++) {
            int s = it * 256 + tid;
            *(float4*)(gb + s * 16) = *(const float4*)(sS + s * 16);
        }
    } else {
        // scatter rows back to ORIGINAL voxel order via nbr[13] (orig index)
        #pragma unroll 1
        for (int p = 0; p < 2; p++) {
            __syncthreads();
            if ((wv >> 1) == p) {
                int lw = wv & 1;
                #pragma unroll
                for (int nt = 0; nt < 2; nt++) {
                    int cn = nt * 32 + ml;
                    float sc = gg[cn] * rsqrtf(vv[cn] + EPSV);
                    float sh = (bb[cn] - mm[cn]) * sc + bee[cn];
                    #pragma unroll
                    for (int r = 0; r < 16; r++) {
                        int rowl = lw * 32 + (r & 3) + 8 * (r >> 2) + 4 * g;
                        float y = fmaxf(acc[nt][r] * sc + sh, 0.f);
                        *(float*)(sS + rowl * 256 + cn * 4) = y;
                    }
                }
            }
            __syncthreads();
            #pragma unroll
            for (int it = 0; it < 4; it++) {
                int s = it * 256 + tid;
                int o = nbr[13 * (size_t)NV + vbase + p * 64 + (s >> 4)];
                *(float4*)((char*)outp + (size_t)o * 256 + (s & 15) * 16)
                    = *(const float4*)(sS + s * 16);
            }
        }
    }
}

extern "C" void kernel_launch(void* const* d_in, const int* in_sizes, int n_in,
                              void* d_out, int out_size, void* d_ws, size_t ws_size,
                              hipStream_t stream) {
    (void)in_sizes; (void)n_in; (void)out_size; (void)ws_size;
    const float* feats = (const float*)d_in[0];
    const int4* coords = (const int4*)d_in[1];
    const float* w1 = (const float*)d_in[2];
    const float* b1 = (const float*)d_in[3];
    const float* g1 = (const float*)d_in[4];
    const float* be1 = (const float*)d_in[5];
    const float* m1 = (const float*)d_in[6];
    const float* v1 = (const float*)d_in[7];
    const float* w2 = (const float*)d_in[8];
    const float* b2 = (const float*)d_in[9];
    const float* g2 = (const float*)d_in[10];
    const float* be2 = (const float*)d_in[11];
    const float* m2 = (const float*)d_in[12];
    const float* v2 = (const float*)d_in[13];
    const float* w3 = (const float*)d_in[14];
    const float* b3 = (const float*)d_in[15];
    const float* g3 = (const float*)d_in[16];
    const float* be3 = (const float*)d_in[17];
    const float* m3 = (const float*)d_in[18];
    const float* v3 = (const float*)d_in[19];

    char* ws = (char*)d_ws;
    int* nbr  = (int*)(ws + OFF_NBR);
    f16* x1   = (f16*)(ws + OFF_X1);
    f16* x2   = (f16*)(ws + OFF_X2);
    int* tab  = (int*)(ws + OFF_TAB);
    int* hist = (int*)(ws + OFF_HIST);
    float* fs = (float*)(ws + OFF_FS);
    f16* w2t  = (f16*)(ws + OFF_W2T);
    f16* w3t  = (f16*)(ws + OFF_W3T);
    f16* zrow = (f16*)(ws + OFF_ZERO);

    k_init<<<4096, 256, 0, stream>>>(w2, w3, tab, w2t, w3t, zrow, hist);
    k_hist<<<(NV + 255) / 256, 256, 0, stream>>>(coords, hist);
    k_scan<<<1, 1024, 0, stream>>>(hist);
    k_rank<<<(NV + 255) / 256, 256, 0, stream>>>(coords, feats, hist, tab, nbr, fs);
    k_nbr2<<<(NV + 255) / 256, 256, 0, stream>>>(coords, tab, nbr);
    k_layer1<<<(NV + 255) / 256, 256, 0, stream>>>(fs, nbr, w1, b1, g1, be1, m1, v1, x1);
    const int convgrid = NV / 128;  // 3125, exact
    k_conv<false><<<convgrid, 256, 0, stream>>>(x1, w2t, nbr, zrow, b2, g2, be2, m2, v2, (void*)x2);
    k_conv<true><<<convgrid, 256, 0, stream>>>(x2, w3t, nbr, zrow, b3, g3, be3, m3, v3, d_out);
}